// Round 5
// baseline (419.168 us; speedup 1.0000x reference)
//
#include <hip/hip_runtime.h>
#include <cstdint>
#include <cstddef>

constexpr int N = 50000;      // nodes
constexpr int D = 256;        // D_IN == D_OUT
constexpr int E = 400000;     // edges per relation
constexpr int R = 4;          // relations
constexpr int N4 = N * R;     // per-(relation,node) counter space
constexpr int AROWS = 50048;  // 391 * 128, padded M
constexpr int KCAT = 1280;    // 4 msg planes + loop plane

constexpr int SLICES = 8;        // dst-space slices (one per XCD)
constexpr int SLICE_SZ = N / SLICES;   // 6250
constexpr int NCHUNK = 16;
constexpr int CHUNK = E / NCHUNK;      // 25000

constexpr int SCAN_CHUNK = 1024;
constexpr int NSCAN4 = (N4 + SCAN_CHUNK - 1) / SCAN_CHUNK;  // 196

typedef _Float16 f16x8 __attribute__((ext_vector_type(8)));
typedef _Float16 f16x4 __attribute__((ext_vector_type(4)));
typedef float f32x4 __attribute__((ext_vector_type(4)));

// ---------------------------------------------------------------------------
// Stacked transposed weights: WT[c][k], c in [0,256), k in [0,1280):
//   k < 1024 -> W_{k/256}[k%256][c], else loop_weight[k-1024][c]. fp16.
// ---------------------------------------------------------------------------
__global__ __launch_bounds__(256)
void wt_build_kernel(const float* __restrict__ w, const float* __restrict__ lw,
                     _Float16* __restrict__ wt) {
    const int i = blockIdx.x * blockDim.x + threadIdx.x;  // c*1280 + k
    if (i >= 256 * KCAT) return;
    const int c = i / KCAT;
    const int k = i - c * KCAT;
    const float v = (k < 1024) ? w[((k >> 8) << 16) + ((k & 255) << 8) + c]
                               : lw[((k - 1024) << 8) + c];
    wt[i] = (_Float16)v;
}

// ---------------------------------------------------------------------------
// x fp32 -> fp16: always into A's loop columns [1024,1280); optionally also
// into a compact [N][256] plane (used by gather for L3 locality).
// ---------------------------------------------------------------------------
__global__ __launch_bounds__(256)
void convert_x_kernel(const float* __restrict__ x, _Float16* __restrict__ A,
                      _Float16* __restrict__ xh_compact) {
    const long i = (long)blockIdx.x * blockDim.x + threadIdx.x;  // per 8 elems
    if (i >= (long)N * (D / 8)) return;
    const long n = i >> 5;
    const int c8 = (int)(i & 31) << 3;
    const float4* s = reinterpret_cast<const float4*>(x + n * D + c8);
    const float4 a = s[0], b = s[1];
    f16x8 v;
    v[0] = (_Float16)a.x; v[1] = (_Float16)a.y;
    v[2] = (_Float16)a.z; v[3] = (_Float16)a.w;
    v[4] = (_Float16)b.x; v[5] = (_Float16)b.y;
    v[6] = (_Float16)b.z; v[7] = (_Float16)b.w;
    *reinterpret_cast<f16x8*>(A + n * KCAT + 1024 + c8) = v;
    if (xh_compact)
        *reinterpret_cast<f16x8*>(xh_compact + n * D + c8) = v;
}

// ---------------------------------------------------------------------------
// XCD-sliced CSR build. blockIdx.x&7 selects a dst slice; assuming round-robin
// block->XCD dispatch, each slice's cnt/pos/src16 lines live in ONE XCD's L2
// (perf-only assumption — correctness holds regardless via device atomics).
// ---------------------------------------------------------------------------
__global__ __launch_bounds__(256)
void count_x_kernel(const int* __restrict__ edges, int* __restrict__ cnt) {
    const int r = blockIdx.y;
    const int slice = blockIdx.x & 7;
    const int chunk = blockIdx.x >> 3;
    const int lo = slice * SLICE_SZ;
    const int hi = lo + SLICE_SZ;
    const int* dst = edges + (r * 2 + 1) * E;
    const int beg = chunk * CHUNK;
    for (int i = beg + threadIdx.x; i < beg + CHUNK; i += 256) {
        const int d = dst[i];
        if (d >= lo && d < hi) atomicAdd(&cnt[r * N + d], 1);
    }
}

__global__ __launch_bounds__(256)
void fill_x_kernel(const int* __restrict__ edges, int* __restrict__ pos,
                   ushort* __restrict__ src16) {
    const int r = blockIdx.y;
    const int slice = blockIdx.x & 7;
    const int chunk = blockIdx.x >> 3;
    const int lo = slice * SLICE_SZ;
    const int hi = lo + SLICE_SZ;
    const int* srcp = edges + r * 2 * E;
    const int* dstp = srcp + E;
    const int beg = chunk * CHUNK;
    for (int i = beg + threadIdx.x; i < beg + CHUNK; i += 256) {
        const int d = dstp[i];
        if (d >= lo && d < hi) {
            const int p = atomicAdd(&pos[r * N + d], 1);
            src16[p] = (ushort)srcp[i];
        }
    }
}

__global__ __launch_bounds__(256)
void scan_a_kernel(const int* __restrict__ cnt, int* __restrict__ excl,
                   int* __restrict__ blocksums) {
    __shared__ int s[256];
    const int t = threadIdx.x;
    const int base = blockIdx.x * SCAN_CHUNK;
    int v[4], sum = 0;
#pragma unroll
    for (int i = 0; i < 4; ++i) {
        const int idx = base + t * 4 + i;
        v[i] = (idx < N4) ? cnt[idx] : 0;
        sum += v[i];
    }
    s[t] = sum;
    __syncthreads();
#pragma unroll
    for (int off = 1; off < 256; off <<= 1) {
        int val = (t >= off) ? s[t - off] : 0;
        __syncthreads();
        s[t] += val;
        __syncthreads();
    }
    int run = s[t] - sum;
#pragma unroll
    for (int i = 0; i < 4; ++i) {
        const int idx = base + t * 4 + i;
        if (idx < N4) excl[idx] = run;
        run += v[i];
    }
    if (t == 0) blocksums[blockIdx.x] = s[255];
}

__global__ __launch_bounds__(256)
void scan_b_kernel(int* __restrict__ bs, int nb) {
    __shared__ int s[256];
    const int t = threadIdx.x;
    const int v = (t < nb) ? bs[t] : 0;
    s[t] = v;
    __syncthreads();
#pragma unroll
    for (int off = 1; off < 256; off <<= 1) {
        int x = (t >= off) ? s[t - off] : 0;
        __syncthreads();
        s[t] += x;
        __syncthreads();
    }
    if (t < nb) bs[t] = s[t] - v;
}

__global__ __launch_bounds__(256)
void scan_c_kernel(int* __restrict__ row_ptr, const int* __restrict__ blocksums,
                   int* __restrict__ pos) {
    const int i = blockIdx.x * blockDim.x + threadIdx.x;
    if (i >= N4) return;
    const int rp = row_ptr[i] + blocksums[i >> 10];
    row_ptr[i] = rp;
    pos[i] = rp;
    if (i == 0) row_ptr[N4] = R * E;
}

// ---------------------------------------------------------------------------
// Gather: wave per (relation,node) pair w = r*N+n. Sum fp16 x-rows of
// in-neighbors (fp32 acc), normalize by 1/max(deg,1), write fp16 msg into
// A[n][r*256 + ...]. xh working set is 25.6 MB (compact) -> L3-resident.
// ---------------------------------------------------------------------------
__global__ __launch_bounds__(256)
void gather_kernel(const _Float16* __restrict__ xh, long xlda,
                   const int* __restrict__ row_ptr,
                   const ushort* __restrict__ src16, _Float16* __restrict__ A) {
    const int w = (blockIdx.x * blockDim.x + threadIdx.x) >> 6;
    const int lane = threadIdx.x & 63;
    if (w >= N4) return;
    const int beg = row_ptr[w];
    const int end = row_ptr[w + 1];
    const int r = w / N;
    const int n = w - r * N;

    float4 acc = make_float4(0.f, 0.f, 0.f, 0.f);
    const int lo4 = lane * 4;
    int j = beg;
    for (; j + 3 < end; j += 4) {
        const int s0 = src16[j], s1 = src16[j + 1];
        const int s2 = src16[j + 2], s3 = src16[j + 3];
        const f16x4 v0 = *reinterpret_cast<const f16x4*>(xh + (long)s0 * xlda + lo4);
        const f16x4 v1 = *reinterpret_cast<const f16x4*>(xh + (long)s1 * xlda + lo4);
        const f16x4 v2 = *reinterpret_cast<const f16x4*>(xh + (long)s2 * xlda + lo4);
        const f16x4 v3 = *reinterpret_cast<const f16x4*>(xh + (long)s3 * xlda + lo4);
        acc.x += (float)v0[0] + (float)v1[0] + (float)v2[0] + (float)v3[0];
        acc.y += (float)v0[1] + (float)v1[1] + (float)v2[1] + (float)v3[1];
        acc.z += (float)v0[2] + (float)v1[2] + (float)v2[2] + (float)v3[2];
        acc.w += (float)v0[3] + (float)v1[3] + (float)v2[3] + (float)v3[3];
    }
    for (; j < end; ++j) {
        const int s0 = src16[j];
        const f16x4 v0 = *reinterpret_cast<const f16x4*>(xh + (long)s0 * xlda + lo4);
        acc.x += (float)v0[0];
        acc.y += (float)v0[1];
        acc.z += (float)v0[2];
        acc.w += (float)v0[3];
    }
    const float rs = 1.0f / fmaxf((float)(end - beg), 1.0f);
    f16x4 o;
    o[0] = (_Float16)(acc.x * rs);
    o[1] = (_Float16)(acc.y * rs);
    o[2] = (_Float16)(acc.z * rs);
    o[3] = (_Float16)(acc.w * rs);
    *reinterpret_cast<f16x4*>(A + (long)n * KCAT + r * 256 + lo4) = o;
}

// ---------------------------------------------------------------------------
// out[N,256] = tanh( A[AROWS,1280] @ WT[256,1280]^T + bias ), fp32 accum/out.
// 128x128 tile, 4 waves, BK=32, k-subtiled LDS [4][128][8] (conflict-free).
// Rows >= N in A hold stale/poison data: harmless (outputs store-guarded,
// MFMA output row i depends only on A row i).
// ---------------------------------------------------------------------------
__global__ __launch_bounds__(256)
void gemm_final_kernel(const _Float16* __restrict__ A,
                       const _Float16* __restrict__ WT,
                       const float* __restrict__ bias, float* __restrict__ C) {
    __shared__ _Float16 As[4][128][8];
    __shared__ _Float16 Bs[4][128][8];

    const int t = threadIdx.x;
    const int lane = t & 63;
    const int w = t >> 6;
    const int wr = w >> 1;
    const int wc = w & 1;
    const long m0 = (long)blockIdx.x * 128;
    const int n0 = blockIdx.y * 128;

    const int srow = t >> 1;
    const int half = t & 1;
    const int skg = half * 2;
    const _Float16* Ag = A + (m0 + srow) * KCAT + half * 16;
    const _Float16* Bg = WT + (long)(n0 + srow) * KCAT + half * 16;

    f32x4 acc[4][4];
#pragma unroll
    for (int i = 0; i < 4; ++i)
#pragma unroll
        for (int j = 0; j < 4; ++j) acc[i][j] = (f32x4){0.f, 0.f, 0.f, 0.f};

    const int kg = lane >> 4;
    const int rr = lane & 15;

    for (int k0 = 0; k0 < KCAT; k0 += 32) {
        const uint4 av0 = *reinterpret_cast<const uint4*>(Ag + k0);
        const uint4 av1 = *reinterpret_cast<const uint4*>(Ag + k0 + 8);
        const uint4 bv0 = *reinterpret_cast<const uint4*>(Bg + k0);
        const uint4 bv1 = *reinterpret_cast<const uint4*>(Bg + k0 + 8);
        __syncthreads();
        *reinterpret_cast<uint4*>(&As[skg + 0][srow][0]) = av0;
        *reinterpret_cast<uint4*>(&As[skg + 1][srow][0]) = av1;
        *reinterpret_cast<uint4*>(&Bs[skg + 0][srow][0]) = bv0;
        *reinterpret_cast<uint4*>(&Bs[skg + 1][srow][0]) = bv1;
        __syncthreads();

        f16x8 af[4], bf[4];
#pragma unroll
        for (int f = 0; f < 4; ++f) {
            af[f] = *reinterpret_cast<const f16x8*>(&As[kg][wr * 64 + f * 16 + rr][0]);
            bf[f] = *reinterpret_cast<const f16x8*>(&Bs[kg][wc * 64 + f * 16 + rr][0]);
        }
#pragma unroll
        for (int i = 0; i < 4; ++i)
#pragma unroll
            for (int j = 0; j < 4; ++j)
                acc[i][j] = __builtin_amdgcn_mfma_f32_16x16x32_f16(
                    af[i], bf[j], acc[i][j], 0, 0, 0);
    }

    const int crow0 = (lane >> 4) * 4;
    const int ccol = lane & 15;
#pragma unroll
    for (int i = 0; i < 4; ++i) {
        const long row = m0 + wr * 64 + i * 16 + crow0;
#pragma unroll
        for (int j = 0; j < 4; ++j) {
            const int col = n0 + wc * 64 + j * 16 + ccol;
            const float b = bias[col];
#pragma unroll
            for (int q = 0; q < 4; ++q) {
                const long rgl = row + q;
                if (rgl < N) C[rgl * 256 + col] = tanhf(acc[i][j][q] + b);
            }
        }
    }
}

// ---------------------------------------------------------------------------
extern "C" void kernel_launch(void* const* d_in, const int* in_sizes, int n_in,
                              void* d_out, int out_size, void* d_ws, size_t ws_size,
                              hipStream_t stream) {
    const float* x           = (const float*)d_in[0];
    const int*   edges       = (const int*)d_in[1];   // [4][2][400000] int32
    const float* weight      = (const float*)d_in[2]; // [4][256][256]
    const float* loop_weight = (const float*)d_in[3]; // [256][256]
    const float* h_bias      = (const float*)d_in[4]; // [256]
    float*       out         = (float*)d_out;
    (void)in_sizes; (void)n_in; (void)out_size;

    size_t off = 0;
    auto carve = [&](size_t bytes) -> void* {
        void* p = (char*)d_ws + off;
        off = (off + bytes + 255) & ~(size_t)255;
        return p;
    };

    const size_t a_bytes  = (size_t)AROWS * KCAT * sizeof(_Float16);  // 128.1 MB
    const size_t xh_bytes = (size_t)N * D * sizeof(_Float16);         // 25.6 MB
    const size_t fixed_bytes = (size_t)KCAT * 256 * sizeof(_Float16)  // WT
                             + (size_t)R * E * sizeof(ushort)         // src16
                             + (size_t)N4 * sizeof(int) * 3           // cnt,row_ptr,pos (+slack)
                             + 4096 + 8 * 256;
    const bool compact_xh = (ws_size >= a_bytes + xh_bytes + fixed_bytes);

    _Float16* A         = (_Float16*)carve(a_bytes);
    _Float16* xh        = compact_xh ? (_Float16*)carve(xh_bytes) : (A + 1024);
    const long xlda     = compact_xh ? 256 : KCAT;
    _Float16* WT        = (_Float16*)carve((size_t)KCAT * 256 * sizeof(_Float16));
    ushort*   src16     = (ushort*)carve((size_t)R * E * sizeof(ushort));
    int*      cnt       = (int*)carve((size_t)N4 * sizeof(int));
    int*      row_ptr   = (int*)carve((size_t)(N4 + 1) * sizeof(int));
    int*      pos       = (int*)carve((size_t)N4 * sizeof(int));
    int*      blocksums = (int*)carve(1024);

    hipMemsetAsync(cnt, 0, (size_t)N4 * sizeof(int), stream);
    wt_build_kernel<<<(256 * KCAT + 255) / 256, 256, 0, stream>>>(weight, loop_weight, WT);
    convert_x_kernel<<<(N * (D / 8) + 255) / 256, 256, 0, stream>>>(
        x, A, compact_xh ? xh : nullptr);

    // XCD-sliced CSR build
    count_x_kernel<<<dim3(SLICES * NCHUNK, R), 256, 0, stream>>>(edges, cnt);
    scan_a_kernel<<<NSCAN4, 256, 0, stream>>>(cnt, row_ptr, blocksums);
    scan_b_kernel<<<1, 256, 0, stream>>>(blocksums, NSCAN4);
    scan_c_kernel<<<(N4 + 255) / 256, 256, 0, stream>>>(row_ptr, blocksums, pos);
    fill_x_kernel<<<dim3(SLICES * NCHUNK, R), 256, 0, stream>>>(edges, pos, src16);

    // msg planes into A columns [0,1024)
    gather_kernel<<<(N4 * 64) / 256, 256, 0, stream>>>(xh, xlda, row_ptr, src16, A);

    // out = tanh(A @ Wcat + bias)
    gemm_final_kernel<<<dim3(AROWS / 128, 2), 256, 0, stream>>>(A, WT, h_bias, out);
}

// Round 6
// 373.549 us; speedup vs baseline: 1.1221x; 1.1221x over previous
//
#include <hip/hip_runtime.h>
#include <cstdint>
#include <cstddef>

constexpr int N = 50000;      // nodes
constexpr int D = 256;        // D_IN == D_OUT
constexpr int E = 400000;     // edges per relation
constexpr int R = 4;          // relations
constexpr int N4 = N * R;     // (relation,node) pairs
constexpr int AROWS = 50048;  // 391 * 128, padded M
constexpr int ACOLS = 1024;   // 4 msg planes (loop plane lives in xh)
constexpr int KCAT = 1280;    // GEMM K = 4 msg planes + loop plane
constexpr int MAXOVF = 16384;

typedef _Float16 f16x8 __attribute__((ext_vector_type(8)));
typedef _Float16 f16x4 __attribute__((ext_vector_type(4)));
typedef float f32x4 __attribute__((ext_vector_type(4)));

// ---------------------------------------------------------------------------
// Stacked transposed weights: WT[c][k], c in [0,256), k in [0,1280):
//   k < 1024 -> W_{k/256}[k%256][c], else loop_weight[k-1024][c]. fp16.
// ---------------------------------------------------------------------------
__global__ __launch_bounds__(256)
void wt_build_kernel(const float* __restrict__ w, const float* __restrict__ lw,
                     _Float16* __restrict__ wt) {
    const int i = blockIdx.x * blockDim.x + threadIdx.x;  // c*1280 + k
    if (i >= 256 * KCAT) return;
    const int c = i / KCAT;
    const int k = i - c * KCAT;
    const float v = (k < 1024) ? w[((k >> 8) << 16) + ((k & 255) << 8) + c]
                               : lw[((k - 1024) << 8) + c];
    wt[i] = (_Float16)v;
}

// ---------------------------------------------------------------------------
// x fp32 -> compact fp16 plane xh[N][256]
// ---------------------------------------------------------------------------
__global__ __launch_bounds__(256)
void convert_x_kernel(const float* __restrict__ x, _Float16* __restrict__ xh) {
    const long i = (long)blockIdx.x * blockDim.x + threadIdx.x;  // per 8 elems
    if (i >= (long)N * (D / 8)) return;
    const long n = i >> 5;
    const int c8 = (int)(i & 31) << 3;
    const float4* s = reinterpret_cast<const float4*>(x + n * D + c8);
    const float4 a = s[0], b = s[1];
    f16x8 v;
    v[0] = (_Float16)a.x; v[1] = (_Float16)a.y;
    v[2] = (_Float16)a.z; v[3] = (_Float16)a.w;
    v[4] = (_Float16)b.x; v[5] = (_Float16)b.y;
    v[6] = (_Float16)b.z; v[7] = (_Float16)b.w;
    *reinterpret_cast<f16x8*>(xh + n * D + c8) = v;
}

// ---------------------------------------------------------------------------
// Single-pass padded-bucket adjacency build (no scan, no fill pass):
//   p = atomicAdd(cnt[w]); p < maxdeg -> slots[w*maxdeg+p] = src
//   else spill to overflow list (statistically never at maxdeg=64, deg~Poi(8);
//   handled correctly regardless).
// ---------------------------------------------------------------------------
__global__ __launch_bounds__(256)
void build_kernel(const int* __restrict__ edges, int* __restrict__ cnt,
                  ushort* __restrict__ slots, int maxdeg,
                  int2* __restrict__ ovf, int* __restrict__ ovf_n) {
    const int r = blockIdx.y;
    const int* srcp = edges + r * 2 * E;
    const int* dstp = srcp + E;
    int i = blockIdx.x * blockDim.x + threadIdx.x;
    const int stride = gridDim.x * blockDim.x;
    for (; i < E; i += stride) {
        const int s = srcp[i];
        const int w = r * N + dstp[i];
        const int p = atomicAdd(&cnt[w], 1);
        if (p < maxdeg) {
            slots[(long)w * maxdeg + p] = (ushort)s;
        } else {
            const int o = atomicAdd(ovf_n, 1);
            if (o < MAXOVF) ovf[o] = make_int2(w, s);
        }
    }
}

// ---------------------------------------------------------------------------
// Gather: wave per (relation,node) pair w = r*N+n. Sum fp16 x-rows of
// in-neighbors (fp32 acc), normalize by 1/max(deg,1), write fp16 msg into
// A[n][r*256 + ...]. xh working set 25.6 MB -> L2/L3-resident.
// ---------------------------------------------------------------------------
__global__ __launch_bounds__(256)
void gather_kernel(const _Float16* __restrict__ xh, const int* __restrict__ cnt,
                   const ushort* __restrict__ slots, int maxdeg,
                   const int2* __restrict__ ovf, const int* __restrict__ ovf_n,
                   _Float16* __restrict__ A) {
    const int w = (blockIdx.x * blockDim.x + threadIdx.x) >> 6;
    const int lane = threadIdx.x & 63;
    if (w >= N4) return;
    const int deg = cnt[w];
    const int m = (deg < maxdeg) ? deg : maxdeg;
    const ushort* sl = slots + (long)w * maxdeg;
    const int lo4 = lane * 4;

    float4 acc = make_float4(0.f, 0.f, 0.f, 0.f);
    int j = 0;
    for (; j + 3 < m; j += 4) {
        const int s0 = sl[j], s1 = sl[j + 1], s2 = sl[j + 2], s3 = sl[j + 3];
        const f16x4 v0 = *reinterpret_cast<const f16x4*>(xh + (long)s0 * D + lo4);
        const f16x4 v1 = *reinterpret_cast<const f16x4*>(xh + (long)s1 * D + lo4);
        const f16x4 v2 = *reinterpret_cast<const f16x4*>(xh + (long)s2 * D + lo4);
        const f16x4 v3 = *reinterpret_cast<const f16x4*>(xh + (long)s3 * D + lo4);
        acc.x += (float)v0[0] + (float)v1[0] + (float)v2[0] + (float)v3[0];
        acc.y += (float)v0[1] + (float)v1[1] + (float)v2[1] + (float)v3[1];
        acc.z += (float)v0[2] + (float)v1[2] + (float)v2[2] + (float)v3[2];
        acc.w += (float)v0[3] + (float)v1[3] + (float)v2[3] + (float)v3[3];
    }
    for (; j < m; ++j) {
        const int s0 = sl[j];
        const f16x4 v0 = *reinterpret_cast<const f16x4*>(xh + (long)s0 * D + lo4);
        acc.x += (float)v0[0];
        acc.y += (float)v0[1];
        acc.z += (float)v0[2];
        acc.w += (float)v0[3];
    }
    if (deg > maxdeg) {  // correctness path; never taken for Poisson(8) degrees
        const int on = min(*ovf_n, MAXOVF);
        for (int o = 0; o < on; ++o) {
            const int2 e = ovf[o];
            if (e.x == w) {
                const f16x4 v0 =
                    *reinterpret_cast<const f16x4*>(xh + (long)e.y * D + lo4);
                acc.x += (float)v0[0];
                acc.y += (float)v0[1];
                acc.z += (float)v0[2];
                acc.w += (float)v0[3];
            }
        }
    }
    const float rs = 1.0f / fmaxf((float)deg, 1.0f);
    f16x4 o;
    o[0] = (_Float16)(acc.x * rs);
    o[1] = (_Float16)(acc.y * rs);
    o[2] = (_Float16)(acc.z * rs);
    o[3] = (_Float16)(acc.w * rs);
    const int r = w / N;
    const int n = w - r * N;
    *reinterpret_cast<f16x4*>(A + (long)n * ACOLS + r * 256 + lo4) = o;
}

// ---------------------------------------------------------------------------
// out[N,256] = tanh( [A | xh] @ WT^T + bias ), fp32 accum/out.
// BM=128, BN=256 (single n-pass: A read once), BK=32, 4 waves (2x2),
// k-subtiled LDS [4][rows][8] (conflict-free ds_read_b128).
// A rows >= N hold garbage: harmless (MFMA row-independence + guarded store).
// ---------------------------------------------------------------------------
__global__ __launch_bounds__(256)
void gemm_final_kernel(const _Float16* __restrict__ A,
                       const _Float16* __restrict__ xh,
                       const _Float16* __restrict__ WT,
                       const float* __restrict__ bias, float* __restrict__ C) {
    __shared__ _Float16 As[4][128][8];
    __shared__ _Float16 Bs[4][256][8];

    const int t = threadIdx.x;
    const int lane = t & 63;
    const int w = t >> 6;
    const int wr = w >> 1;   // wave row (0..1): 64 output rows each
    const int wc = w & 1;    // wave col (0..1): 128 output cols each
    const long m0 = (long)blockIdx.x * 128;

    const int srow = t >> 1;       // A stage row 0..127
    const int half = t & 1;        // which 16-wide k half
    const int skg = half * 2;
    const long arow = m0 + srow;
    const _Float16* Bg = WT + (long)t * KCAT;  // B stage row = output col t

    f32x4 acc[4][8];
#pragma unroll
    for (int i = 0; i < 4; ++i)
#pragma unroll
        for (int j = 0; j < 8; ++j) acc[i][j] = (f32x4){0.f, 0.f, 0.f, 0.f};

    const int kg = lane >> 4;
    const int rr = lane & 15;

    for (int k0 = 0; k0 < KCAT; k0 += 32) {
        const _Float16* Ap = (k0 < ACOLS)
                                 ? A + arow * ACOLS + k0 + half * 16
                                 : xh + arow * D + (k0 - ACOLS) + half * 16;
        const uint4 av0 = *reinterpret_cast<const uint4*>(Ap);
        const uint4 av1 = *reinterpret_cast<const uint4*>(Ap + 8);
        const uint4 bv0 = *reinterpret_cast<const uint4*>(Bg + k0);
        const uint4 bv1 = *reinterpret_cast<const uint4*>(Bg + k0 + 8);
        const uint4 bv2 = *reinterpret_cast<const uint4*>(Bg + k0 + 16);
        const uint4 bv3 = *reinterpret_cast<const uint4*>(Bg + k0 + 24);
        __syncthreads();  // previous iteration's frag reads done
        *reinterpret_cast<uint4*>(&As[skg + 0][srow][0]) = av0;
        *reinterpret_cast<uint4*>(&As[skg + 1][srow][0]) = av1;
        *reinterpret_cast<uint4*>(&Bs[0][t][0]) = bv0;
        *reinterpret_cast<uint4*>(&Bs[1][t][0]) = bv1;
        *reinterpret_cast<uint4*>(&Bs[2][t][0]) = bv2;
        *reinterpret_cast<uint4*>(&Bs[3][t][0]) = bv3;
        __syncthreads();

        f16x8 af[4], bf[8];
#pragma unroll
        for (int f = 0; f < 4; ++f)
            af[f] = *reinterpret_cast<const f16x8*>(&As[kg][wr * 64 + f * 16 + rr][0]);
#pragma unroll
        for (int g = 0; g < 8; ++g)
            bf[g] = *reinterpret_cast<const f16x8*>(&Bs[kg][wc * 128 + g * 16 + rr][0]);
#pragma unroll
        for (int i = 0; i < 4; ++i)
#pragma unroll
            for (int j = 0; j < 8; ++j)
                acc[i][j] = __builtin_amdgcn_mfma_f32_16x16x32_f16(
                    af[i], bf[j], acc[i][j], 0, 0, 0);
    }

    // epilogue: C/D map col=lane&15, row=(lane>>4)*4+reg
    const int crow0 = (lane >> 4) * 4;
    const int ccol = lane & 15;
#pragma unroll
    for (int i = 0; i < 4; ++i) {
        const long row = m0 + wr * 64 + i * 16 + crow0;
#pragma unroll
        for (int j = 0; j < 8; ++j) {
            const int col = wc * 128 + j * 16 + ccol;
            const float b = bias[col];
#pragma unroll
            for (int q = 0; q < 4; ++q) {
                const long rgl = row + q;
                if (rgl < N) C[rgl * 256 + col] = tanhf(acc[i][j][q] + b);
            }
        }
    }
}

// ---------------------------------------------------------------------------
extern "C" void kernel_launch(void* const* d_in, const int* in_sizes, int n_in,
                              void* d_out, int out_size, void* d_ws, size_t ws_size,
                              hipStream_t stream) {
    const float* x           = (const float*)d_in[0];
    const int*   edges       = (const int*)d_in[1];   // [4][2][400000] int32
    const float* weight      = (const float*)d_in[2]; // [4][256][256]
    const float* loop_weight = (const float*)d_in[3]; // [256][256]
    const float* h_bias      = (const float*)d_in[4]; // [256]
    float*       out         = (float*)d_out;
    (void)in_sizes; (void)n_in; (void)out_size;

    size_t off = 0;
    auto carve = [&](size_t bytes) -> void* {
        void* p = (char*)d_ws + off;
        off = (off + bytes + 255) & ~(size_t)255;
        return p;
    };

    const size_t a_bytes  = (size_t)AROWS * ACOLS * sizeof(_Float16);  // 102.5 MB
    const size_t xh_bytes = (size_t)N * D * sizeof(_Float16);          // 25.6 MB
    const size_t fixed    = (size_t)KCAT * 256 * sizeof(_Float16)      // WT
                          + (size_t)N4 * sizeof(int)                   // cnt
                          + MAXOVF * sizeof(int2) + 4096;
    // maxdeg=64 needs ~155 MB (proven available in r5: >=160 MB); 32 as fallback.
    const int maxdeg =
        (ws_size >= a_bytes + xh_bytes + (size_t)N4 * 64 * sizeof(ushort) + fixed)
            ? 64 : 32;

    _Float16* A     = (_Float16*)carve(a_bytes);
    _Float16* xh    = (_Float16*)carve(xh_bytes);
    ushort*   slots = (ushort*)carve((size_t)N4 * maxdeg * sizeof(ushort));
    _Float16* WT    = (_Float16*)carve((size_t)KCAT * 256 * sizeof(_Float16));
    int*      cnt   = (int*)carve((size_t)N4 * sizeof(int));
    int*      ovf_n = (int*)carve(256);
    int2*     ovf   = (int2*)carve(MAXOVF * sizeof(int2));

    hipMemsetAsync(cnt, 0, (size_t)N4 * sizeof(int), stream);
    hipMemsetAsync(ovf_n, 0, sizeof(int), stream);

    wt_build_kernel<<<(256 * KCAT + 255) / 256, 256, 0, stream>>>(weight, loop_weight, WT);
    convert_x_kernel<<<(N * (D / 8) + 255) / 256, 256, 0, stream>>>(x, xh);

    // single-pass adjacency build
    build_kernel<<<dim3(512, R), 256, 0, stream>>>(edges, cnt, slots, maxdeg, ovf, ovf_n);

    // msg planes into A columns [0,1024)
    gather_kernel<<<(N4 * 64) / 256, 256, 0, stream>>>(xh, cnt, slots, maxdeg,
                                                       ovf, ovf_n, A);

    // out = tanh([A | xh] @ Wcat + bias)
    gemm_final_kernel<<<AROWS / 128, 256, 0, stream>>>(A, xh, WT, h_bias, out);
}